// Round 1
// 76.394 us; speedup vs baseline: 1.0421x; 1.0421x over previous
//
#include <hip/hip_runtime.h>

// Fused gaussian rasterizer, v2.
// Change vs v1 (79.6us total, kernel ~39us): phase 4 was latency-bound on a
// dependent LDS chain (s_order[m] -> s_all[g]) at 1 wave/SIMD, ~200+cy/iter.
// Now: records live in registers after preprocess, survivors are ranked via a
// single packed 64-bit key ((z_bits<<32)|g, exact stable-argsort order) read
// affinely from a compacted key array, and scattered into a depth-SORTED
// record array s_srt. Phase 4 then streams s_srt with affine addresses,
// software-pipelined 2 records ahead, plus wave-level early exit when all 64
// pixels are saturated (T < 1e-5, error bound 1e-5 << passing absmax 3.9e-3).

constexpr int IMG_H = 256;
constexpr int IMG_W = 256;
constexpr int MAXN  = 512;
constexpr int TW    = 16;
constexpr int TH    = 16;
constexpr int NTHR  = TW * TH;   // 256 threads, 4 waves

__global__ __launch_bounds__(NTHR) void fused_raster_kernel(
    const float* __restrict__ positions,
    const float* __restrict__ cov3d,
    const float* __restrict__ opacities,
    const float* __restrict__ colors,
    const float* __restrict__ Km,
    const float* __restrict__ Rm,
    const float* __restrict__ tv,
    float* __restrict__ out)
{
    // Depth-sorted records, 3 x float4 each:
    //  [0] = {mx, my, h00, h01}          h00 = -0.5*inv00, h01 = -inv01
    //  [1] = {h11, opac, col_r, col_g}   h11 = -0.5*inv11
    //  [2] = {col_b, bbox_pack, 0, 0}    bbox tile-relative, 4x5 bits
    // +4 pad records: sentinels at K,K+1 (zeroed -> in=false -> a=0) and
    // prefetch overrun space.
    __shared__ float4 s_srt[(MAXN + 4) * 3];            // 24.8 KB
    __shared__ unsigned long long s_key[MAXN];          // 4 KB
    __shared__ int s_total;

    const int tid = threadIdx.y * TW + threadIdx.x;     // 0..255
    if (tid == 0) s_total = 0;

    const int tx0i = blockIdx.x * TW;
    const int ty0i = blockIdx.y * TH;
    const float tx0 = (float)tx0i;
    const float ty0 = (float)ty0i;

    const float R00 = Rm[0], R01 = Rm[1], R02 = Rm[2];
    const float R10 = Rm[3], R11 = Rm[4], R12 = Rm[5];
    const float R20 = Rm[6], R21 = Rm[7], R22 = Rm[8];
    const float t0 = tv[0], t1 = tv[1], t2 = tv[2];
    const float K00 = Km[0], K01 = Km[1], K02 = Km[2];
    const float K10 = Km[3], K11 = Km[4], K12 = Km[5];
    const float K20 = Km[6], K21 = Km[7], K22 = Km[8];
    const float fx = K00, fy = K11;

    __syncthreads();   // s_total init visible before shared atomics

    // --- Phase 1: preprocess 2 gaussians/thread, keep records in REGISTERS.
    float r_mx[2], r_my[2], r_h00[2], r_h01[2], r_h11[2];
    float r_op[2], r_cr[2], r_cg[2], r_cb[2];
    float r_xmin[2], r_xmax[2], r_ymin[2], r_ymax[2];
    unsigned long long r_key[2];
    bool r_hit[2];

    #pragma unroll
    for (int k = 0; k < 2; ++k) {
        const int g = k * NTHR + tid;

        const float px = positions[g*3+0];
        const float py = positions[g*3+1];
        const float pz = positions[g*3+2];

        const float cx = R00*px + R01*py + R02*pz + t0;
        const float cy = R10*px + R11*py + R12*pz + t1;
        const float cz = R20*px + R21*py + R22*pz + t2;

        const float pr0 = K00*cx + K01*cy + K02*cz;
        const float pr1 = K10*cx + K11*cy + K12*cz;
        const float pr2 = K20*cx + K21*cy + K22*cz;
        const float mx = pr0 / pr2;
        const float my = pr1 / pr2;

        const float invz  = 1.0f / cz;
        const float invz2 = invz * invz;
        const float j00 =  fx * invz;
        const float j02 = -fx * cx * invz2;
        const float j11 =  fy * invz;
        const float j12 = -fy * cy * invz2;

        const float C00 = cov3d[g*9+0], C01 = cov3d[g*9+1], C02 = cov3d[g*9+2];
        const float C10 = cov3d[g*9+3], C11 = cov3d[g*9+4], C12 = cov3d[g*9+5];
        const float C20 = cov3d[g*9+6], C21 = cov3d[g*9+7], C22 = cov3d[g*9+8];

        const float T100 = R00*C00 + R01*C10 + R02*C20;
        const float T101 = R00*C01 + R01*C11 + R02*C21;
        const float T102 = R00*C02 + R01*C12 + R02*C22;
        const float T110 = R10*C00 + R11*C10 + R12*C20;
        const float T111 = R10*C01 + R11*C11 + R12*C21;
        const float T112 = R10*C02 + R11*C12 + R12*C22;
        const float T120 = R20*C00 + R21*C10 + R22*C20;
        const float T121 = R20*C01 + R21*C11 + R22*C21;
        const float T122 = R20*C02 + R21*C12 + R22*C22;
        const float M00 = T100*R00 + T101*R01 + T102*R02;
        const float M01 = T100*R10 + T101*R11 + T102*R12;
        const float M02 = T100*R20 + T101*R21 + T102*R22;
        const float M11 = T110*R10 + T111*R11 + T112*R12;
        const float M12 = T110*R20 + T111*R21 + T112*R22;
        const float M20 = T120*R00 + T121*R01 + T122*R02;
        const float M21 = T120*R10 + T121*R11 + T122*R12;
        const float M22 = T120*R20 + T121*R21 + T122*R22;

        const float v00 = M00*j00 + M02*j02;
        const float v02 = M20*j00 + M22*j02;
        const float v10 = M01*j11 + M02*j12;
        const float v11 = M11*j11 + M12*j12;
        const float v12 = M21*j11 + M22*j12;

        const float va = j00*v00 + j02*v02 + 0.3f;
        const float vb = j00*v10 + j02*v12;
        const float vc = j11*v11 + j12*v12 + 0.3f;

        const float det  = fmaxf(va*vc - vb*vb, 1e-8f);
        const float idet = 1.0f / det;
        const float inv00 =  vc * idet;
        const float inv01 = -vb * idet;
        const float inv11 =  va * idet;

        const float half_diff = (va - vc) * 0.5f;
        const float disc = fmaxf(half_diff*half_diff + vb*vb, 1e-8f);
        const float max_eig = (va + vc) * 0.5f + sqrtf(disc);
        const float radii = 3.0f * sqrtf(max_eig);

        const float x_min = fmaxf(0.0f, truncf(mx - radii));
        const float x_max = fminf((float)IMG_W, truncf(mx + radii) + 1.0f);
        const float y_min = fmaxf(0.0f, truncf(my - radii));
        const float y_max = fminf((float)IMG_H, truncf(my + radii) + 1.0f);

        r_mx[k] = mx;  r_my[k] = my;
        r_h00[k] = -0.5f*inv00;  r_h01[k] = -inv01;  r_h11[k] = -0.5f*inv11;
        r_op[k] = opacities[g];
        r_cr[k] = colors[g*3+0]; r_cg[k] = colors[g*3+1]; r_cb[k] = colors[g*3+2];
        r_xmin[k] = x_min; r_xmax[k] = x_max;
        r_ymin[k] = y_min; r_ymax[k] = y_max;

        // z in [2,6] > 0, so float bits sort like the float; tie-break by g
        // reproduces the reference's STABLE argsort exactly.
        r_key[k] = ((unsigned long long)__float_as_uint(cz) << 32) | (unsigned)g;

        const bool hit = (x_min < tx0 + (float)TW) && (x_max > tx0) &&
                         (y_min < ty0 + (float)TH) && (y_max > ty0);
        r_hit[k] = hit;
        if (hit) {
            const int pos = atomicAdd(&s_total, 1);   // unordered is fine:
            s_key[pos] = r_key[k];                    // rank is order-free
        }
    }
    __syncthreads();
    const int K = s_total;

    // --- Phase 2: rank = #{survivor keys < mine}. Affine b64 broadcast reads,
    // fully pipelineable; both own-gaussian ranks in one pass over K.
    int rank0 = 0, rank1 = 0;
    for (int j = 0; j < K; ++j) {
        const unsigned long long kj = s_key[j];
        rank0 += (kj < r_key[0]) ? 1 : 0;
        rank1 += (kj < r_key[1]) ? 1 : 0;
    }

    // --- Phase 3: scatter register records to their depth rank; pack the
    // tile-clamped integer bbox (values are exact small-int floats).
    #pragma unroll
    for (int k = 0; k < 2; ++k) {
        if (r_hit[k]) {
            const int xm = max(0,  (int)r_xmin[k] - tx0i);
            const int xM = min(TW, (int)r_xmax[k] - tx0i);
            const int ym = max(0,  (int)r_ymin[k] - ty0i);
            const int yM = min(TH, (int)r_ymax[k] - ty0i);
            const unsigned pk = (unsigned)xm | ((unsigned)xM << 5)
                              | ((unsigned)ym << 10) | ((unsigned)yM << 15);
            const int rk = (k == 0) ? rank0 : rank1;
            s_srt[rk*3+0] = make_float4(r_mx[k], r_my[k], r_h00[k], r_h01[k]);
            s_srt[rk*3+1] = make_float4(r_h11[k], r_op[k], r_cr[k], r_cg[k]);
            s_srt[rk*3+2] = make_float4(r_cb[k], __uint_as_float(pk), 0.0f, 0.0f);
        }
    }
    // Zero sentinels at ranks K, K+1: pack=0 -> in=false -> a=0 (no-op record).
    if (tid < 6) s_srt[K*3 + tid] = make_float4(0.0f, 0.0f, 0.0f, 0.0f);
    __syncthreads();

    // --- Phase 4: front-to-back composite. Affine LDS reads, software-
    // pipelined 2 records ahead; unroll-by-2; wave-uniform early exit.
    const int tix = threadIdx.x, tiy = threadIdx.y;
    const float fxp = (float)(tx0i + tix);
    const float fyp = (float)(ty0i + tiy);

    float T = 1.0f, accr = 0.0f, accg = 0.0f, accb = 0.0f;

    float4 A0 = s_srt[0], A1 = s_srt[1], A2 = s_srt[2];
    float4 B0 = s_srt[3], B1 = s_srt[4], B2 = s_srt[5];

    for (int m = 0; m < K; m += 2) {
        const int pf = (m + 2) * 3;
        const float4 C0 = s_srt[pf+0], C1 = s_srt[pf+1], C2 = s_srt[pf+2];
        const float4 D0 = s_srt[pf+3], D1 = s_srt[pf+4], D2 = s_srt[pf+5];

        {   // record m
            const unsigned pk = __float_as_uint(A2.y);
            const bool in = (tix >= (int)(pk & 31u)) & (tix < (int)((pk >> 5) & 31u))
                          & (tiy >= (int)((pk >> 10) & 31u)) & (tiy < (int)((pk >> 15) & 31u));
            const float dx = fxp - A0.x;
            const float dy = fyp - A0.y;
            const float e = A0.z*dx*dx + A0.w*dx*dy + A1.x*dy*dy;
            const float a = in ? A1.y * __expf(e) : 0.0f;
            const float w = T * a;
            accr = fmaf(w, A1.z, accr);
            accg = fmaf(w, A1.w, accg);
            accb = fmaf(w, A2.x, accb);
            T *= (1.0f - a);
        }
        {   // record m+1 (sentinel no-op if m+1 == K)
            const unsigned pk = __float_as_uint(B2.y);
            const bool in = (tix >= (int)(pk & 31u)) & (tix < (int)((pk >> 5) & 31u))
                          & (tiy >= (int)((pk >> 10) & 31u)) & (tiy < (int)((pk >> 15) & 31u));
            const float dx = fxp - B0.x;
            const float dy = fyp - B0.y;
            const float e = B0.z*dx*dx + B0.w*dx*dy + B1.x*dy*dy;
            const float a = in ? B1.y * __expf(e) : 0.0f;
            const float w = T * a;
            accr = fmaf(w, B1.z, accr);
            accg = fmaf(w, B1.w, accg);
            accb = fmaf(w, B2.x, accb);
            T *= (1.0f - a);
        }

        A0 = C0; A1 = C1; A2 = C2;
        B0 = D0; B1 = D1; B2 = D2;

        // All 64 pixels of this wave saturated -> remaining contribution
        // < 1e-5 per channel. Waves exit independently (no barrier below).
        if (!__any(T > 1.0e-5f)) break;
    }

    const int pix = ((ty0i + tiy) * IMG_W + (tx0i + tix)) * 3;
    out[pix + 0] = accr;
    out[pix + 1] = accg;
    out[pix + 2] = accb;
}

extern "C" void kernel_launch(void* const* d_in, const int* in_sizes, int n_in,
                              void* d_out, int out_size, void* d_ws, size_t ws_size,
                              hipStream_t stream)
{
    const float* positions = (const float*)d_in[0];
    const float* cov3d     = (const float*)d_in[1];
    const float* opacities = (const float*)d_in[2];
    const float* colors    = (const float*)d_in[3];
    const float* Km        = (const float*)d_in[4];
    const float* Rm        = (const float*)d_in[5];
    const float* tv        = (const float*)d_in[6];
    float* out = (float*)d_out;

    dim3 block(TW, TH);
    dim3 grid(IMG_W / TW, IMG_H / TH);
    fused_raster_kernel<<<grid, block, 0, stream>>>(
        positions, cov3d, opacities, colors, Km, Rm, tv, out);
}

// Round 2
// 72.172 us; speedup vs baseline: 1.1031x; 1.0585x over previous
//
#include <hip/hip_runtime.h>

// Fused gaussian rasterizer, v3.
// Change vs v2 (76.4us total): at grid=256 blocks of 256 thr there was exactly
// 1 wave/SIMD -> zero latency hiding, and the front-to-back compositing chain
// (strict prefix dependence in T) was fully serial over K records.
// v3 uses 512-thread blocks: compositing is a monoid
//   (acc,T)_F o (acc,T)_B = (acc_F + T_F*acc_B, T_F*T_B)
// so waves 0-3 composite the FRONT half of the depth-sorted list for the four
// 16x4 pixel strips while waves 4-7 composite the BACK half (local T=1);
// an exact LDS combine merges them. Serial chain halved, occupancy doubled
// (2 waves/SIMD), preprocess = 1 gaussian/thread, compaction via per-wave
// ballot (8 LDS atomics instead of up to 512).

constexpr int IMG_H = 256;
constexpr int IMG_W = 256;
constexpr int MAXN  = 512;
constexpr int TW    = 16;
constexpr int TH    = 16;
constexpr int NTHR  = 512;   // 8 waves

__global__ __launch_bounds__(NTHR) void fused_raster_kernel(
    const float* __restrict__ positions,
    const float* __restrict__ cov3d,
    const float* __restrict__ opacities,
    const float* __restrict__ colors,
    const float* __restrict__ Km,
    const float* __restrict__ Rm,
    const float* __restrict__ tv,
    float* __restrict__ out)
{
    // Depth-sorted records, 3 x float4 each:
    //  [0] = {mx, my, h00, h01}          h00 = -0.5*inv00, h01 = -inv01
    //  [1] = {h11, opac, col_r, col_g}   h11 = -0.5*inv11
    //  [2] = {col_b, bbox_pack, 0, 0}    bbox tile-relative, 4x5 bits
    __shared__ float4 s_srt[(MAXN + 4) * 3];            // 24.8 KB
    __shared__ unsigned long long s_key[MAXN];          // 4 KB
    __shared__ float4 s_comb[TW * TH];                  // 4 KB back-half partials
    __shared__ int s_total;

    const int tix  = threadIdx.x;          // 0..15
    const int ty   = threadIdx.y;          // 0..31
    const int tid  = ty * TW + tix;        // 0..511
    const int lane = tid & 63;
    const int half = ty >> 4;              // 0 = front chunk, 1 = back chunk
    const int py   = ty & 15;              // pixel row within tile

    if (tid == 0) s_total = 0;

    const int tx0i = blockIdx.x * TW;
    const int ty0i = blockIdx.y * TH;
    const float tx0 = (float)tx0i;
    const float ty0 = (float)ty0i;

    const float R00 = Rm[0], R01 = Rm[1], R02 = Rm[2];
    const float R10 = Rm[3], R11 = Rm[4], R12 = Rm[5];
    const float R20 = Rm[6], R21 = Rm[7], R22 = Rm[8];
    const float t0 = tv[0], t1 = tv[1], t2 = tv[2];
    const float K00 = Km[0], K01 = Km[1], K02 = Km[2];
    const float K10 = Km[3], K11 = Km[4], K12 = Km[5];
    const float K20 = Km[6], K21 = Km[7], K22 = Km[8];
    const float fx = K00, fy = K11;

    __syncthreads();   // s_total init visible before shared atomics

    // --- Phase 1: preprocess 1 gaussian/thread, record kept in registers. ---
    const int g = tid;

    const float px = positions[g*3+0];
    const float py3 = positions[g*3+1];
    const float pz = positions[g*3+2];

    const float cx = R00*px + R01*py3 + R02*pz + t0;
    const float cy = R10*px + R11*py3 + R12*pz + t1;
    const float cz = R20*px + R21*py3 + R22*pz + t2;

    const float pr0 = K00*cx + K01*cy + K02*cz;
    const float pr1 = K10*cx + K11*cy + K12*cz;
    const float pr2 = K20*cx + K21*cy + K22*cz;
    const float mx = pr0 / pr2;
    const float my = pr1 / pr2;

    const float invz  = 1.0f / cz;
    const float invz2 = invz * invz;
    const float j00 =  fx * invz;
    const float j02 = -fx * cx * invz2;
    const float j11 =  fy * invz;
    const float j12 = -fy * cy * invz2;

    const float C00 = cov3d[g*9+0], C01 = cov3d[g*9+1], C02 = cov3d[g*9+2];
    const float C10 = cov3d[g*9+3], C11 = cov3d[g*9+4], C12 = cov3d[g*9+5];
    const float C20 = cov3d[g*9+6], C21 = cov3d[g*9+7], C22 = cov3d[g*9+8];

    const float T100 = R00*C00 + R01*C10 + R02*C20;
    const float T101 = R00*C01 + R01*C11 + R02*C21;
    const float T102 = R00*C02 + R01*C12 + R02*C22;
    const float T110 = R10*C00 + R11*C10 + R12*C20;
    const float T111 = R10*C01 + R11*C11 + R12*C21;
    const float T112 = R10*C02 + R11*C12 + R12*C22;
    const float T120 = R20*C00 + R21*C10 + R22*C20;
    const float T121 = R20*C01 + R21*C11 + R22*C21;
    const float T122 = R20*C02 + R21*C12 + R22*C22;
    const float M00 = T100*R00 + T101*R01 + T102*R02;
    const float M01 = T100*R10 + T101*R11 + T102*R12;
    const float M02 = T100*R20 + T101*R21 + T102*R22;
    const float M11 = T110*R10 + T111*R11 + T112*R12;
    const float M12 = T110*R20 + T111*R21 + T112*R22;
    const float M20 = T120*R00 + T121*R01 + T122*R02;
    const float M21 = T120*R10 + T121*R11 + T122*R12;
    const float M22 = T120*R20 + T121*R21 + T122*R22;

    const float v00 = M00*j00 + M02*j02;
    const float v02 = M20*j00 + M22*j02;
    const float v10 = M01*j11 + M02*j12;
    const float v11 = M11*j11 + M12*j12;
    const float v12 = M21*j11 + M22*j12;

    const float va = j00*v00 + j02*v02 + 0.3f;
    const float vb = j00*v10 + j02*v12;
    const float vc = j11*v11 + j12*v12 + 0.3f;

    const float det  = fmaxf(va*vc - vb*vb, 1e-8f);
    const float idet = 1.0f / det;
    const float inv00 =  vc * idet;
    const float inv01 = -vb * idet;
    const float inv11 =  va * idet;

    const float half_diff = (va - vc) * 0.5f;
    const float disc = fmaxf(half_diff*half_diff + vb*vb, 1e-8f);
    const float max_eig = (va + vc) * 0.5f + sqrtf(disc);
    const float radii = 3.0f * sqrtf(max_eig);

    const float x_min = fmaxf(0.0f, truncf(mx - radii));
    const float x_max = fminf((float)IMG_W, truncf(mx + radii) + 1.0f);
    const float y_min = fmaxf(0.0f, truncf(my - radii));
    const float y_max = fminf((float)IMG_H, truncf(my + radii) + 1.0f);

    // z in [2,6] > 0 so float bits sort like the float; tie-break by g
    // reproduces the reference's STABLE argsort exactly.
    const unsigned long long key =
        ((unsigned long long)__float_as_uint(cz) << 32) | (unsigned)g;

    const bool hit = (x_min < tx0 + (float)TW) && (x_max > tx0) &&
                     (y_min < ty0 + (float)TH) && (y_max > ty0);

    // Per-wave ballot compaction: 8 LDS atomics total, order-free (rank sort).
    {
        const unsigned long long mb = __ballot(hit);
        int base = 0;
        if (lane == 0 && mb) base = atomicAdd(&s_total, __popcll(mb));
        base = __shfl(base, 0);
        if (hit) {
            const int pos = base + __popcll(mb & ((1ull << lane) - 1ull));
            s_key[pos] = key;
        }
    }
    __syncthreads();
    const int K = s_total;

    // --- Phase 2: rank = #{survivor keys < mine}; affine b64 broadcasts. ---
    int rank = 0;
    for (int j = 0; j < K; ++j)
        rank += (s_key[j] < key) ? 1 : 0;

    // --- Phase 3: scatter register record to its depth rank. ---
    if (hit) {
        const int xm = max(0,  (int)x_min - tx0i);
        const int xM = min(TW, (int)x_max - tx0i);
        const int ym = max(0,  (int)y_min - ty0i);
        const int yM = min(TH, (int)y_max - ty0i);
        const unsigned pk = (unsigned)xm | ((unsigned)xM << 5)
                          | ((unsigned)ym << 10) | ((unsigned)yM << 15);
        s_srt[rank*3+0] = make_float4(mx, my, -0.5f*inv00, -inv01);
        s_srt[rank*3+1] = make_float4(-0.5f*inv11, opacities[g],
                                      colors[g*3+0], colors[g*3+1]);
        s_srt[rank*3+2] = make_float4(colors[g*3+2], __uint_as_float(pk),
                                      0.0f, 0.0f);
    }
    // Zero sentinels at ranks K, K+1 (pack=0 -> in=false -> a=0 no-op).
    if (tid < 6) s_srt[K*3 + tid] = make_float4(0.0f, 0.0f, 0.0f, 0.0f);
    __syncthreads();

    // --- Phase 4: split front-to-back compositing across wave halves.
    // Kf = front-chunk length, rounded up to EVEN so the front loop never
    // touches the sentinel; back chunk ends at K where sentinels live.
    int Kf = (K + 1) >> 1;
    Kf += (Kf & 1);
    if (Kf > K) Kf = K + (K & 1);   // degenerate tiny-K: keep ranges valid
    const int mStart = half ? Kf : 0;
    const int mEnd   = half ? K  : Kf;

    const float fxp = (float)(tx0i + tix);
    const float fyp = (float)(ty0i + py);

    float T = 1.0f, accr = 0.0f, accg = 0.0f, accb = 0.0f;

    const int sb = mStart * 3;
    float4 A0 = s_srt[sb+0], A1 = s_srt[sb+1], A2 = s_srt[sb+2];
    float4 B0 = s_srt[sb+3], B1 = s_srt[sb+4], B2 = s_srt[sb+5];

    for (int m = mStart; m < mEnd; m += 2) {
        const int pf = (m + 2) * 3;
        const float4 C0 = s_srt[pf+0], C1 = s_srt[pf+1], C2 = s_srt[pf+2];
        const float4 D0 = s_srt[pf+3], D1 = s_srt[pf+4], D2 = s_srt[pf+5];

        {   // record m
            const unsigned pk = __float_as_uint(A2.y);
            const bool in = (tix >= (int)(pk & 31u)) & (tix < (int)((pk >> 5) & 31u))
                          & (py >= (int)((pk >> 10) & 31u)) & (py < (int)((pk >> 15) & 31u));
            const float dx = fxp - A0.x;
            const float dy = fyp - A0.y;
            const float e = A0.z*dx*dx + A0.w*dx*dy + A1.x*dy*dy;
            const float a = in ? A1.y * __expf(e) : 0.0f;
            const float w = T * a;
            accr = fmaf(w, A1.z, accr);
            accg = fmaf(w, A1.w, accg);
            accb = fmaf(w, A2.x, accb);
            T *= (1.0f - a);
        }
        {   // record m+1 (sentinel no-op when m+1 == K)
            const unsigned pk = __float_as_uint(B2.y);
            const bool in = (tix >= (int)(pk & 31u)) & (tix < (int)((pk >> 5) & 31u))
                          & (py >= (int)((pk >> 10) & 31u)) & (py < (int)((pk >> 15) & 31u));
            const float dx = fxp - B0.x;
            const float dy = fyp - B0.y;
            const float e = B0.z*dx*dx + B0.w*dx*dy + B1.x*dy*dy;
            const float a = in ? B1.y * __expf(e) : 0.0f;
            const float w = T * a;
            accr = fmaf(w, B1.z, accr);
            accg = fmaf(w, B1.w, accg);
            accb = fmaf(w, B2.x, accb);
            T *= (1.0f - a);
        }

        A0 = C0; A1 = C1; A2 = C2;
        B0 = D0; B1 = D1; B2 = D2;

        // Early exit valid for BOTH halves: remaining contributions within a
        // chunk are scaled by local T (and back-chunk output additionally by
        // T_front <= 1), so error < 1e-5 << tolerance. Break, don't return:
        // everyone must reach the combine barrier.
        if (!__any(T > 1.0e-5f)) break;
    }

    // --- Phase 5: exact monoid combine: front o back, then store. ---
    if (half == 1) s_comb[py * TW + tix] = make_float4(accr, accg, accb, T);
    __syncthreads();
    if (half == 0) {
        const float4 b = s_comb[py * TW + tix];
        accr = fmaf(T, b.x, accr);
        accg = fmaf(T, b.y, accg);
        accb = fmaf(T, b.z, accb);
        const int pix = ((ty0i + py) * IMG_W + (tx0i + tix)) * 3;
        out[pix + 0] = accr;
        out[pix + 1] = accg;
        out[pix + 2] = accb;
    }
}

extern "C" void kernel_launch(void* const* d_in, const int* in_sizes, int n_in,
                              void* d_out, int out_size, void* d_ws, size_t ws_size,
                              hipStream_t stream)
{
    const float* positions = (const float*)d_in[0];
    const float* cov3d     = (const float*)d_in[1];
    const float* opacities = (const float*)d_in[2];
    const float* colors    = (const float*)d_in[3];
    const float* Km        = (const float*)d_in[4];
    const float* Rm        = (const float*)d_in[5];
    const float* tv        = (const float*)d_in[6];
    float* out = (float*)d_out;

    dim3 block(TW, 2 * TH);                 // 512 threads, 8 waves
    dim3 grid(IMG_W / TW, IMG_H / TH);      // 256 tiles
    fused_raster_kernel<<<grid, block, 0, stream>>>(
        positions, cov3d, opacities, colors, Km, Rm, tv, out);
}

// Round 3
// 70.809 us; speedup vs baseline: 1.1243x; 1.0192x over previous
//
#include <hip/hip_runtime.h>

// Fused gaussian rasterizer, v4.
// Change vs v3 (72.2us total; residual over the untouchable 40us harness fill
// = 32.3us): v3's 2-way depth split bought 4us -> phase 4 is still
// latency-bound on the serial composite chain at only 2 waves/SIMD.
// v4: 1024-thread blocks, 4-way depth split of the sorted list using the
// compositing monoid (a,T)o(a',T') = (a + T a', T T'):
//   chunk c handled by waves 4c..4c+3 (full 16x16 tile per chunk),
//   exact 3-partial LDS combine at the end.
// Serial chain K/2 -> K/4; occupancy 2 -> 4 waves/SIMD (128-VGPR budget).

constexpr int IMG_H = 256;
constexpr int IMG_W = 256;
constexpr int MAXN  = 512;
constexpr int TW    = 16;
constexpr int TH    = 16;
constexpr int NTHR  = 1024;   // 16 waves, 4 waves/SIMD

__global__ __launch_bounds__(NTHR) void fused_raster_kernel(
    const float* __restrict__ positions,
    const float* __restrict__ cov3d,
    const float* __restrict__ opacities,
    const float* __restrict__ colors,
    const float* __restrict__ Km,
    const float* __restrict__ Rm,
    const float* __restrict__ tv,
    float* __restrict__ out)
{
    // Depth-sorted records, 3 x float4 each:
    //  [0] = {mx, my, h00, h01}          h00 = -0.5*inv00, h01 = -inv01
    //  [1] = {h11, opac, col_r, col_g}   h11 = -0.5*inv11
    //  [2] = {col_b, bbox_pack, 0, 0}    bbox tile-relative, 4x5 bits
    __shared__ float4 s_srt[(MAXN + 4) * 3];            // 24.8 KB
    __shared__ unsigned long long s_key[MAXN];          // 4 KB
    __shared__ float4 s_comb[3 * TW * TH];              // 12 KB chunk partials
    __shared__ int s_total;

    const int tix   = threadIdx.x;          // 0..15
    const int ty    = threadIdx.y;          // 0..63
    const int tid   = ty * TW + tix;        // 0..1023
    const int lane  = tid & 63;
    const int chunk = ty >> 4;              // 0..3 depth chunk
    const int py    = ty & 15;              // pixel row within tile

    if (tid == 0) s_total = 0;

    const int tx0i = blockIdx.x * TW;
    const int ty0i = blockIdx.y * TH;
    const float tx0 = (float)tx0i;
    const float ty0 = (float)ty0i;

    const float R00 = Rm[0], R01 = Rm[1], R02 = Rm[2];
    const float R10 = Rm[3], R11 = Rm[4], R12 = Rm[5];
    const float R20 = Rm[6], R21 = Rm[7], R22 = Rm[8];
    const float t0 = tv[0], t1 = tv[1], t2 = tv[2];
    const float K00 = Km[0], K01 = Km[1], K02 = Km[2];
    const float K10 = Km[3], K11 = Km[4], K12 = Km[5];
    const float K20 = Km[6], K21 = Km[7], K22 = Km[8];
    const float fx = K00, fy = K11;

    __syncthreads();   // s_total init visible before shared atomics

    // --- Phase 1: preprocess 1 gaussian/thread (threads 512..1023 idle). ---
    const bool active = (tid < MAXN);
    const int g = active ? tid : 0;

    float mx = 0.f, my = 0.f, inv00 = 0.f, inv01 = 0.f, inv11 = 0.f;
    float x_min = 0.f, x_max = 0.f, y_min = 0.f, y_max = 0.f;
    unsigned long long key = ~0ull;
    bool hit = false;

    if (active) {
        const float px = positions[g*3+0];
        const float pyy = positions[g*3+1];
        const float pz = positions[g*3+2];

        const float cx = R00*px + R01*pyy + R02*pz + t0;
        const float cy = R10*px + R11*pyy + R12*pz + t1;
        const float cz = R20*px + R21*pyy + R22*pz + t2;

        const float pr0 = K00*cx + K01*cy + K02*cz;
        const float pr1 = K10*cx + K11*cy + K12*cz;
        const float pr2 = K20*cx + K21*cy + K22*cz;
        mx = pr0 / pr2;
        my = pr1 / pr2;

        const float invz  = 1.0f / cz;
        const float invz2 = invz * invz;
        const float j00 =  fx * invz;
        const float j02 = -fx * cx * invz2;
        const float j11 =  fy * invz;
        const float j12 = -fy * cy * invz2;

        const float C00 = cov3d[g*9+0], C01 = cov3d[g*9+1], C02 = cov3d[g*9+2];
        const float C10 = cov3d[g*9+3], C11 = cov3d[g*9+4], C12 = cov3d[g*9+5];
        const float C20 = cov3d[g*9+6], C21 = cov3d[g*9+7], C22 = cov3d[g*9+8];

        const float T100 = R00*C00 + R01*C10 + R02*C20;
        const float T101 = R00*C01 + R01*C11 + R02*C21;
        const float T102 = R00*C02 + R01*C12 + R02*C22;
        const float T110 = R10*C00 + R11*C10 + R12*C20;
        const float T111 = R10*C01 + R11*C11 + R12*C21;
        const float T112 = R10*C02 + R11*C12 + R12*C22;
        const float T120 = R20*C00 + R21*C10 + R22*C20;
        const float T121 = R20*C01 + R21*C11 + R22*C21;
        const float T122 = R20*C02 + R21*C12 + R22*C22;
        const float M00 = T100*R00 + T101*R01 + T102*R02;
        const float M01 = T100*R10 + T101*R11 + T102*R12;
        const float M02 = T100*R20 + T101*R21 + T102*R22;
        const float M11 = T110*R10 + T111*R11 + T112*R12;
        const float M12 = T110*R20 + T111*R21 + T112*R22;
        const float M20 = T120*R00 + T121*R01 + T122*R02;
        const float M21 = T120*R10 + T121*R11 + T122*R12;
        const float M22 = T120*R20 + T121*R21 + T122*R22;

        const float v00 = M00*j00 + M02*j02;
        const float v02 = M20*j00 + M22*j02;
        const float v10 = M01*j11 + M02*j12;
        const float v11 = M11*j11 + M12*j12;
        const float v12 = M21*j11 + M22*j12;

        const float va = j00*v00 + j02*v02 + 0.3f;
        const float vb = j00*v10 + j02*v12;
        const float vc = j11*v11 + j12*v12 + 0.3f;

        const float det  = fmaxf(va*vc - vb*vb, 1e-8f);
        const float idet = 1.0f / det;
        inv00 =  vc * idet;
        inv01 = -vb * idet;
        inv11 =  va * idet;

        const float half_diff = (va - vc) * 0.5f;
        const float disc = fmaxf(half_diff*half_diff + vb*vb, 1e-8f);
        const float max_eig = (va + vc) * 0.5f + sqrtf(disc);
        const float radii = 3.0f * sqrtf(max_eig);

        x_min = fmaxf(0.0f, truncf(mx - radii));
        x_max = fminf((float)IMG_W, truncf(mx + radii) + 1.0f);
        y_min = fmaxf(0.0f, truncf(my - radii));
        y_max = fminf((float)IMG_H, truncf(my + radii) + 1.0f);

        // z in [2,6] > 0 so float bits sort like the float; tie-break by g
        // reproduces the reference's STABLE argsort exactly.
        key = ((unsigned long long)__float_as_uint(cz) << 32) | (unsigned)g;

        hit = (x_min < tx0 + (float)TW) && (x_max > tx0) &&
              (y_min < ty0 + (float)TH) && (y_max > ty0);
    }

    // Per-wave ballot compaction (order-free: rank sort fixes order).
    {
        const unsigned long long mb = __ballot(hit);
        int base = 0;
        if (lane == 0 && mb) base = atomicAdd(&s_total, __popcll(mb));
        base = __shfl(base, 0);
        if (hit) {
            const int pos = base + __popcll(mb & ((1ull << lane) - 1ull));
            s_key[pos] = key;
        }
    }
    __syncthreads();
    const int K = s_total;

    // --- Phase 2: rank = #{survivor keys < mine}; affine b64 broadcasts.
    // Wave-uniform skip for waves with no surviving lane (incl. waves 8-15).
    int rank = 0;
    if (__any(hit)) {
        for (int j = 0; j < K; ++j)
            rank += (s_key[j] < key) ? 1 : 0;
    }

    // --- Phase 3: scatter register record to its depth rank. ---
    if (hit) {
        const int xm = max(0,  (int)x_min - tx0i);
        const int xM = min(TW, (int)x_max - tx0i);
        const int ym = max(0,  (int)y_min - ty0i);
        const int yM = min(TH, (int)y_max - ty0i);
        const unsigned pk = (unsigned)xm | ((unsigned)xM << 5)
                          | ((unsigned)ym << 10) | ((unsigned)yM << 15);
        s_srt[rank*3+0] = make_float4(mx, my, -0.5f*inv00, -inv01);
        s_srt[rank*3+1] = make_float4(-0.5f*inv11, opacities[g],
                                      colors[g*3+0], colors[g*3+1]);
        s_srt[rank*3+2] = make_float4(colors[g*3+2], __uint_as_float(pk),
                                      0.0f, 0.0f);
    }
    // Zero 4 sentinel records at ranks K..K+3 (pack=0 -> in=false -> no-op);
    // covers prefetch overrun and empty-chunk initial prefetch.
    if (tid < 12) s_srt[K*3 + tid] = make_float4(0.0f, 0.0f, 0.0f, 0.0f);
    __syncthreads();

    // --- Phase 4: 4-way depth-split front-to-back compositing.
    // Chunk boundaries rounded UP to even so every nonempty chunk starts even
    // (step-2 loop alignment); clamping to K only produces empty tail chunks.
    const int q1 = min(K, (K/4     + 1) & ~1);
    const int q2 = min(K, (K/2     + 1) & ~1);
    const int q3 = min(K, (3*K/4   + 1) & ~1);
    const int mStart = (chunk == 0) ? 0  : (chunk == 1) ? q1 : (chunk == 2) ? q2 : q3;
    const int mEnd   = (chunk == 0) ? q1 : (chunk == 1) ? q2 : (chunk == 2) ? q3 : K;

    const float fxp = (float)(tx0i + tix);
    const float fyp = (float)(ty0i + py);

    float T = 1.0f, accr = 0.0f, accg = 0.0f, accb = 0.0f;

    const int sb = mStart * 3;
    float4 A0 = s_srt[sb+0], A1 = s_srt[sb+1], A2 = s_srt[sb+2];
    float4 B0 = s_srt[sb+3], B1 = s_srt[sb+4], B2 = s_srt[sb+5];

    for (int m = mStart; m < mEnd; m += 2) {
        const int pf = (m + 2) * 3;
        const float4 C0 = s_srt[pf+0], C1 = s_srt[pf+1], C2 = s_srt[pf+2];
        const float4 D0 = s_srt[pf+3], D1 = s_srt[pf+4], D2 = s_srt[pf+5];

        {   // record m
            const unsigned pk = __float_as_uint(A2.y);
            const bool in = (tix >= (int)(pk & 31u)) & (tix < (int)((pk >> 5) & 31u))
                          & (py >= (int)((pk >> 10) & 31u)) & (py < (int)((pk >> 15) & 31u));
            const float dx = fxp - A0.x;
            const float dy = fyp - A0.y;
            const float e = A0.z*dx*dx + A0.w*dx*dy + A1.x*dy*dy;
            const float a = in ? A1.y * __expf(e) : 0.0f;
            const float w = T * a;
            accr = fmaf(w, A1.z, accr);
            accg = fmaf(w, A1.w, accg);
            accb = fmaf(w, A2.x, accb);
            T *= (1.0f - a);
        }
        {   // record m+1 (sentinel no-op past chunk/list end)
            const unsigned pk = __float_as_uint(B2.y);
            const bool in = (tix >= (int)(pk & 31u)) & (tix < (int)((pk >> 5) & 31u))
                          & (py >= (int)((pk >> 10) & 31u)) & (py < (int)((pk >> 15) & 31u));
            const float dx = fxp - B0.x;
            const float dy = fyp - B0.y;
            const float e = B0.z*dx*dx + B0.w*dx*dy + B1.x*dy*dy;
            const float a = in ? B1.y * __expf(e) : 0.0f;
            const float w = T * a;
            accr = fmaf(w, B1.z, accr);
            accg = fmaf(w, B1.w, accg);
            accb = fmaf(w, B2.x, accb);
            T *= (1.0f - a);
        }

        A0 = C0; A1 = C1; A2 = C2;
        B0 = D0; B1 = D1; B2 = D2;

        // Early exit: remaining contribution within this chunk is scaled by
        // local T (< 1e-5), and downstream chunks' output by upstream T <= 1,
        // so per-channel error < 1e-5 << tolerance. Break (not return):
        // everyone must reach the combine barrier.
        if (!__any(T > 1.0e-5f)) break;
    }

    // --- Phase 5: exact monoid combine c0 o c1 o c2 o c3, then store. ---
    const int idx = py * TW + tix;
    if (chunk != 0) s_comb[(chunk - 1) * (TW*TH) + idx] = make_float4(accr, accg, accb, T);
    __syncthreads();
    if (chunk == 0) {
        const float4 c1 = s_comb[0*(TW*TH) + idx];
        const float4 c2 = s_comb[1*(TW*TH) + idx];
        const float4 c3 = s_comb[2*(TW*TH) + idx];
        // acc23 = c2 + T2*c3 ; acc123 = c1 + T1*acc23 ; acc += T0*acc123
        const float r123 = fmaf(c1.w, fmaf(c2.w, c3.x, c2.x), c1.x);
        const float g123 = fmaf(c1.w, fmaf(c2.w, c3.y, c2.y), c1.y);
        const float b123 = fmaf(c1.w, fmaf(c2.w, c3.z, c2.z), c1.z);
        accr = fmaf(T, r123, accr);
        accg = fmaf(T, g123, accg);
        accb = fmaf(T, b123, accb);
        const int pix = ((ty0i + py) * IMG_W + (tx0i + tix)) * 3;
        out[pix + 0] = accr;
        out[pix + 1] = accg;
        out[pix + 2] = accb;
    }
}

extern "C" void kernel_launch(void* const* d_in, const int* in_sizes, int n_in,
                              void* d_out, int out_size, void* d_ws, size_t ws_size,
                              hipStream_t stream)
{
    const float* positions = (const float*)d_in[0];
    const float* cov3d     = (const float*)d_in[1];
    const float* opacities = (const float*)d_in[2];
    const float* colors    = (const float*)d_in[3];
    const float* Km        = (const float*)d_in[4];
    const float* Rm        = (const float*)d_in[5];
    const float* tv        = (const float*)d_in[6];
    float* out = (float*)d_out;

    dim3 block(TW, 4 * TH);                 // 1024 threads, 16 waves
    dim3 grid(IMG_W / TW, IMG_H / TH);      // 256 tiles
    fused_raster_kernel<<<grid, block, 0, stream>>>(
        positions, cov3d, opacities, colors, Km, Rm, tv, out);
}